// Round 9
// baseline (424.170 us; speedup 1.0000x reference)
//
#include <hip/hip_runtime.h>
#include <math.h>

#define EPS 1e-16f
__device__ __forceinline__ float lrelu(float v) { return v > 0.0f ? v : 0.2f * v; }

// bf16 pack/unpack (RNE; inputs finite)
__device__ __forceinline__ unsigned short f2bf(float f) {
    unsigned u = __float_as_uint(f);
    u += 0x7FFF + ((u >> 16) & 1);
    return (unsigned short)(u >> 16);
}
__device__ __forceinline__ float bf2f(unsigned short s) {
    return __uint_as_float(((unsigned)s) << 16);
}

// ---------------- CSR build ----------------
__global__ void k_zero(int* __restrict__ deg, int N) {
    int i = blockIdx.x * 256 + threadIdx.x;
    if (i < N) deg[i] = 0;
}

// multi-block scan: per-block local inclusive scan + block sums
__global__ __launch_bounds__(1024) void k_scan_local(const int* __restrict__ deg,
                                                     int* __restrict__ rowptr,
                                                     int* __restrict__ blocksum, int N) {
    __shared__ int sdata[1024];
    int i = blockIdx.x * 1024 + threadIdx.x;
    int v = (i < N) ? deg[i] : 0;
    sdata[threadIdx.x] = v;
    __syncthreads();
    for (int off = 1; off < 1024; off <<= 1) {
        int t = (threadIdx.x >= (unsigned)off) ? sdata[threadIdx.x - off] : 0;
        __syncthreads();
        sdata[threadIdx.x] += t;
        __syncthreads();
    }
    if (i < N) rowptr[i + 1] = sdata[threadIdx.x];
    if (threadIdx.x == 1023) blocksum[blockIdx.x] = sdata[1023];
}

// scan_add with inlined block-sum scan (every block redundantly wave-scans <=64 sums)
__global__ void k_scan_add(int* __restrict__ rowptr, const int* __restrict__ blocksum,
                           const int* __restrict__ deg, int* __restrict__ cursor,
                           int N, int nb) {
    __shared__ int sOff[64];
    int t = threadIdx.x;
    if (t < 64) {
        int v = (t < nb) ? blocksum[t] : 0;
        int incl = v;
#pragma unroll
        for (int off = 1; off < 64; off <<= 1) {
            int u = __shfl_up(incl, off);
            if (t >= off) incl += u;
        }
        sOff[t] = incl - v;
    }
    __syncthreads();
    int i = blockIdx.x * 256 + t;
    if (i >= N) return;
    int val = rowptr[i + 1] + sOff[i >> 10];
    rowptr[i + 1] = val;
    cursor[i] = val - deg[i];
    if (i == 0) rowptr[0] = 0;
}

// 8 edges per thread: 8 independent atomic-return chains in flight
__global__ void k_scatter(const int* __restrict__ src, const int* __restrict__ dst,
                          int* __restrict__ cursor, int* __restrict__ ssrc, int E) {
    int e0 = (blockIdx.x * 256 + threadIdx.x) * 8;
    if (e0 >= E) return;
    int4 sa = *((const int4*)(src + e0)),     sb = *((const int4*)(src + e0 + 4));
    int4 da = *((const int4*)(dst + e0)),     db = *((const int4*)(dst + e0 + 4));
    int p0 = atomicAdd(&cursor[da.x], 1);
    int p1 = atomicAdd(&cursor[da.y], 1);
    int p2 = atomicAdd(&cursor[da.z], 1);
    int p3 = atomicAdd(&cursor[da.w], 1);
    int p4 = atomicAdd(&cursor[db.x], 1);
    int p5 = atomicAdd(&cursor[db.y], 1);
    int p6 = atomicAdd(&cursor[db.z], 1);
    int p7 = atomicAdd(&cursor[db.w], 1);
    ssrc[p0] = sa.x; ssrc[p1] = sa.y; ssrc[p2] = sa.z; ssrc[p3] = sa.w;
    ssrc[p4] = sb.x; ssrc[p5] = sb.y; ssrc[p6] = sb.z; ssrc[p7] = sb.w;
}

// ---------------- layer-1 GEMM + deg tail ----------------
// x[N,128] @ W1[128,64] -> h1 (bf16) + fused attention dots. BM=64, BN=64, K chunked 2x64.
// sW[k][n] pitch 64: B-reads are 4-address broadcast (conflict-free b128).
// sX[m][k] pitch 64 with XOR-swizzled k-quads (q ^ ((m>>2)&7)): row-strided b128 A-reads
// land 2-way (free) instead of the 8/16-way any padded pitch gives.
// LDS 48KB -> 3 blocks/CU. deg histogram runs as a per-block tail (overlaps other blocks).
#define FMA4(ci, s, b)                      \
    ci[0] = fmaf(s, b.x, ci[0]);            \
    ci[1] = fmaf(s, b.y, ci[1]);            \
    ci[2] = fmaf(s, b.z, ci[2]);            \
    ci[3] = fmaf(s, b.w, ci[3]);

__global__ __launch_bounds__(256, 3) void k_gemm1_deg(
    const float* __restrict__ x, const float* __restrict__ W1,
    const float* __restrict__ att_src1, const float* __restrict__ att_dst1,
    unsigned short* __restrict__ h1b, float* __restrict__ a_src1, float* __restrict__ a_dst1,
    int N, const int* __restrict__ dst, int* __restrict__ deg, int E) {
    __shared__ float sW[128 * 64];   // [k][n]
    __shared__ float sX[64 * 64];    // [m][k-chunk], swizzled quads
    float4* sW4 = (float4*)sW;
    float4* sX4 = (float4*)sX;
    int t = threadIdx.x;
    int r0 = blockIdx.x * 64;
    int tx = t & 15, ty = t >> 4;

    // stage W1 whole (layout matches row-major exactly)
    for (int i = t; i < 2048; i += 256) sW4[i] = ((const float4*)W1)[i];

    float c[4][4] = {{0.f}};
#pragma unroll
    for (int chunk = 0; chunk < 2; chunk++) {
        // stage x chunk (64 rows x 64 k), swizzled
        for (int i = t; i < 1024; i += 256) {
            int m = i >> 4, q = i & 15;
            int r = r0 + m;
            float4 v = make_float4(0.f, 0.f, 0.f, 0.f);
            if (r < N) v = ((const float4*)(x + (size_t)r * 128))[chunk * 16 + q];
            sX4[m * 16 + (q ^ ((m >> 2) & 7))] = v;
        }
        __syncthreads();
        int kbase = chunk * 64;
#pragma unroll
        for (int kb = 0; kb < 16; kb++) {
            int qs = kb ^ (tx & 7);
            float4 a0 = sX4[(4 * tx + 0) * 16 + qs];
            float4 a1 = sX4[(4 * tx + 1) * 16 + qs];
            float4 a2 = sX4[(4 * tx + 2) * 16 + qs];
            float4 a3 = sX4[(4 * tx + 3) * 16 + qs];
            float4 b0 = sW4[(kbase + 4 * kb + 0) * 16 + ty];
            float4 b1 = sW4[(kbase + 4 * kb + 1) * 16 + ty];
            float4 b2 = sW4[(kbase + 4 * kb + 2) * 16 + ty];
            float4 b3 = sW4[(kbase + 4 * kb + 3) * 16 + ty];
            FMA4(c[0], a0.x, b0) FMA4(c[0], a0.y, b1) FMA4(c[0], a0.z, b2) FMA4(c[0], a0.w, b3)
            FMA4(c[1], a1.x, b0) FMA4(c[1], a1.y, b1) FMA4(c[1], a1.z, b2) FMA4(c[1], a1.w, b3)
            FMA4(c[2], a2.x, b0) FMA4(c[2], a2.y, b1) FMA4(c[2], a2.z, b2) FMA4(c[2], a2.w, b3)
            FMA4(c[3], a3.x, b0) FMA4(c[3], a3.y, b1) FMA4(c[3], a3.z, b2) FMA4(c[3], a3.w, b3)
        }
        __syncthreads();
    }

    // epilogue: h1 as bf16 + fused per-head attention dots (fp32 accumulators)
    float as0 = att_src1[4 * ty + 0], as1 = att_src1[4 * ty + 1],
          as2 = att_src1[4 * ty + 2], as3 = att_src1[4 * ty + 3];
    float ad0 = att_dst1[4 * ty + 0], ad1 = att_dst1[4 * ty + 1],
          ad2 = att_dst1[4 * ty + 2], ad3 = att_dst1[4 * ty + 3];
    float* sPs = sX;                              // reuse sX: [row][17], 2*64*17 floats < 16KB
    float* sPd = sX + 64 * 17;
#pragma unroll
    for (int i = 0; i < 4; i++) {
        int row = 4 * tx + i;
        int r = r0 + row;
        if (r < N) {
            ushort4 hv;
            hv.x = f2bf(c[i][0]); hv.y = f2bf(c[i][1]);
            hv.z = f2bf(c[i][2]); hv.w = f2bf(c[i][3]);
            *((ushort4*)(h1b + (size_t)r * 64 + 4 * ty)) = hv;
        }
        sPs[row * 17 + ty] = fmaf(c[i][0], as0, fmaf(c[i][1], as1, fmaf(c[i][2], as2, c[i][3] * as3)));
        sPd[row * 17 + ty] = fmaf(c[i][0], ad0, fmaf(c[i][1], ad1, fmaf(c[i][2], ad2, c[i][3] * ad3)));
    }
    __syncthreads();
    for (int i = t; i < 512; i += 256) {          // i = row*8 + h
        int row = i >> 3, h = i & 7;
        int r = r0 + row;
        if (r < N) {
            a_src1[r * 8 + h] = sPs[row * 17 + 2 * h] + sPs[row * 17 + 2 * h + 1];
            a_dst1[r * 8 + h] = sPd[row * 17 + 2 * h] + sPd[row * 17 + 2 * h + 1];
        }
    }
    // deg tail: this block's 1024-edge slice, 4 atomics in flight per thread.
    // Overlaps with compute of co-resident blocks; deg pre-zeroed by k_zero (prior launch).
    int e0 = blockIdx.x * 1024 + t * 4;
    if (e0 < E) {
        int4 d4 = *((const int4*)(dst + e0));
        atomicAdd(&deg[d4.x], 1);
        atomicAdd(&deg[d4.y], 1);
        atomicAdd(&deg[d4.z], 1);
        atomicAdd(&deg[d4.w], 1);
    }
}

// ---------------- layer 1: per-dst-node softmax + aggregate (one wave per node) ----------------
// no max subtraction (softmax shift-invariant; logits are O(1)); h1 gathered as bf16
__global__ __launch_bounds__(256) void k_node_agg1(
    const int* __restrict__ rowptr, const int* __restrict__ ssrc,
    const float* __restrict__ a_src1, const float* __restrict__ a_dst1,
    const unsigned short* __restrict__ h1b, const float* __restrict__ bias1,
    float* __restrict__ xx, int N) {
    int d = (blockIdx.x * 256 + threadIdx.x) >> 6;
    int lane = threadIdx.x & 63;
    if (d >= N) return;
    int start = rowptr[d], end = rowptr[d + 1];
    int hcol = lane >> 3;   // head owning this output col
    int h8 = lane & 7;      // head this lane covers in edge-parallel phase
    int eoff = lane >> 3;   // edge-in-chunk this lane covers in edge-parallel phase
    float adst8 = a_dst1[d * 8 + h8];
    float acc0 = 0.0f, acc1 = 0.0f, lsumA = 0.0f;
    int base = start;
    for (; base + 8 <= end; base += 8) {
        int s_l = ssrc[base + eoff];
        float ex_l = __expf(lrelu(a_src1[(size_t)s_l * 8 + h8] + adst8));
        lsumA += ex_l;
        int s0 = __shfl(s_l, 0),  s1 = __shfl(s_l, 8),  s2 = __shfl(s_l, 16), s3 = __shfl(s_l, 24);
        int s4 = __shfl(s_l, 32), s5 = __shfl(s_l, 40), s6 = __shfl(s_l, 48), s7 = __shfl(s_l, 56);
        float f0 = __shfl(ex_l, hcol),      f1 = __shfl(ex_l, 8 + hcol);
        float f2 = __shfl(ex_l, 16 + hcol), f3 = __shfl(ex_l, 24 + hcol);
        float f4 = __shfl(ex_l, 32 + hcol), f5 = __shfl(ex_l, 40 + hcol);
        float f6 = __shfl(ex_l, 48 + hcol), f7 = __shfl(ex_l, 56 + hcol);
        float g0 = bf2f(h1b[(size_t)s0 * 64 + lane]), g1 = bf2f(h1b[(size_t)s1 * 64 + lane]);
        float g2 = bf2f(h1b[(size_t)s2 * 64 + lane]), g3 = bf2f(h1b[(size_t)s3 * 64 + lane]);
        float g4 = bf2f(h1b[(size_t)s4 * 64 + lane]), g5 = bf2f(h1b[(size_t)s5 * 64 + lane]);
        float g6 = bf2f(h1b[(size_t)s6 * 64 + lane]), g7 = bf2f(h1b[(size_t)s7 * 64 + lane]);
        acc0 = fmaf(f0, g0, acc0); acc1 = fmaf(f1, g1, acc1);
        acc0 = fmaf(f2, g2, acc0); acc1 = fmaf(f3, g3, acc1);
        acc0 = fmaf(f4, g4, acc0); acc1 = fmaf(f5, g5, acc1);
        acc0 = fmaf(f6, g6, acc0); acc1 = fmaf(f7, g7, acc1);
    }
    int ecnt = end - base;
    if (ecnt > 0) {
        int s_l = 0; float ex_l = 0.0f;
        if (eoff < ecnt) {
            s_l = ssrc[base + eoff];
            ex_l = __expf(lrelu(a_src1[(size_t)s_l * 8 + h8] + adst8));
        }
        lsumA += ex_l;
        for (int j = 0; j < ecnt; j++) {
            int sj = __shfl(s_l, j * 8);
            float fj = __shfl(ex_l, j * 8 + hcol);
            acc0 = fmaf(fj, bf2f(h1b[(size_t)sj * 64 + lane]), acc0);
        }
    }
    float t = lsumA;
    t += __shfl_xor(t, 8); t += __shfl_xor(t, 16); t += __shfl_xor(t, 32);
    float lsum = __shfl(t, hcol);
    float o = (acc0 + acc1) / (lsum + EPS) + bias1[lane];
    xx[(size_t)d * 64 + lane] = o > 0.0f ? o : expm1f(o);   // ELU
}

// ---------------- layer 2 GEMM: xx[N,64] @ W2[64,40] -> h2 (bf16), + fused attention dots ----
#define LDK2 65
#define LDN2 41
__global__ __launch_bounds__(256, 2) void k_gemm2(
    const float* __restrict__ xx, const float* __restrict__ W2,
    const float* __restrict__ att_src2, const float* __restrict__ att_dst2,
    unsigned short* __restrict__ h2b, float* __restrict__ a_src2, float* __restrict__ a_dst2, int N) {
    __shared__ float sX[64 * LDK2];    // [m][k]
    __shared__ float sW[64 * LDN2];    // [k][n]
    int t = threadIdx.x;
    int r0 = blockIdx.x * 64;
    for (int i = t; i < 640; i += 256) {          // i = k*10 + n4
        int k = i / 10, n4 = i - k * 10;
        float4 v = ((const float4*)W2)[i];
        float* p = sW + k * LDN2 + 4 * n4;
        p[0] = v.x; p[1] = v.y; p[2] = v.z; p[3] = v.w;
    }
    for (int i = t; i < 1024; i += 256) {         // i = m*16 + k4
        int m = i >> 4, k4 = i & 15;
        int r = r0 + m;
        float4 v = make_float4(0.f, 0.f, 0.f, 0.f);
        if (r < N) v = ((const float4*)(xx + (size_t)r * 64))[k4];
        float* p = sX + m * LDK2 + 4 * k4;
        p[0] = v.x; p[1] = v.y; p[2] = v.z; p[3] = v.w;
    }
    __syncthreads();
    int tx = t & 15, ty = t >> 4;
    bool act = ty < 10;
    float c[4][4] = {{0.f}};
    if (act) {
        const float* pA = sX + 4 * tx * LDK2;
        const float* pB = sW + 4 * ty;
#pragma unroll 8
        for (int k = 0; k < 64; k++) {
            float a0 = pA[k], a1 = pA[LDK2 + k], a2 = pA[2 * LDK2 + k], a3 = pA[3 * LDK2 + k];
            const float* pb = pB + k * LDN2;
            float b0 = pb[0], b1 = pb[1], b2 = pb[2], b3 = pb[3];
            c[0][0] = fmaf(a0, b0, c[0][0]); c[0][1] = fmaf(a0, b1, c[0][1]);
            c[0][2] = fmaf(a0, b2, c[0][2]); c[0][3] = fmaf(a0, b3, c[0][3]);
            c[1][0] = fmaf(a1, b0, c[1][0]); c[1][1] = fmaf(a1, b1, c[1][1]);
            c[1][2] = fmaf(a1, b2, c[1][2]); c[1][3] = fmaf(a1, b3, c[1][3]);
            c[2][0] = fmaf(a2, b0, c[2][0]); c[2][1] = fmaf(a2, b1, c[2][1]);
            c[2][2] = fmaf(a2, b2, c[2][2]); c[2][3] = fmaf(a2, b3, c[2][3]);
            c[3][0] = fmaf(a3, b0, c[3][0]); c[3][1] = fmaf(a3, b1, c[3][1]);
            c[3][2] = fmaf(a3, b2, c[3][2]); c[3][3] = fmaf(a3, b3, c[3][3]);
        }
    }
    float as0 = 0.f, as1 = 0.f, as2 = 0.f, as3 = 0.f;
    float ad0 = 0.f, ad1 = 0.f, ad2 = 0.f, ad3 = 0.f;
    if (act) {
        as0 = att_src2[4 * ty + 0]; as1 = att_src2[4 * ty + 1];
        as2 = att_src2[4 * ty + 2]; as3 = att_src2[4 * ty + 3];
        ad0 = att_dst2[4 * ty + 0]; ad1 = att_dst2[4 * ty + 1];
        ad2 = att_dst2[4 * ty + 2]; ad3 = att_dst2[4 * ty + 3];
    }
    __syncthreads();                              // reuse sX as partials [row][11]
    float* sPs = sX;
    float* sPd = sX + 64 * 11;
#pragma unroll
    for (int i = 0; i < 4; i++) {
        int row = 4 * tx + i;
        int r = r0 + row;
        if (act) {
            if (r < N) {
                ushort4 hv;
                hv.x = f2bf(c[i][0]); hv.y = f2bf(c[i][1]);
                hv.z = f2bf(c[i][2]); hv.w = f2bf(c[i][3]);
                *((ushort4*)(h2b + (size_t)r * 40 + 4 * ty)) = hv;
            }
            sPs[row * 11 + ty] = fmaf(c[i][0], as0, fmaf(c[i][1], as1, fmaf(c[i][2], as2, c[i][3] * as3)));
            sPd[row * 11 + ty] = fmaf(c[i][0], ad0, fmaf(c[i][1], ad1, fmaf(c[i][2], ad2, c[i][3] * ad3)));
        }
    }
    __syncthreads();
    if (t < 64) {
        int r = r0 + t;
        if (r < N) {
            float ps = 0.f, pd = 0.f;
#pragma unroll
            for (int j = 0; j < 10; j++) {
                ps += sPs[t * 11 + j];
                pd += sPd[t * 11 + j];
            }
            a_src2[r] = ps;
            a_dst2[r] = pd;
        }
    }
}

// ---------------- layer 2: per-dst-node softmax + aggregate (h2 gathered as bf16) --------
__global__ __launch_bounds__(256) void k_node_agg2(
    const int* __restrict__ rowptr, const int* __restrict__ ssrc,
    const float* __restrict__ a_src2, const float* __restrict__ a_dst2,
    const unsigned short* __restrict__ h2b, const float* __restrict__ bias2,
    float* __restrict__ out, int N) {
    int d = (blockIdx.x * 256 + threadIdx.x) >> 6;
    int lane = threadIdx.x & 63;
    if (d >= N) return;
    int start = rowptr[d], end = rowptr[d + 1];
    float adst = a_dst2[d];
    bool act = lane < 40;
    float acc0 = 0.0f, acc1 = 0.0f, lsumA = 0.0f;
    for (int base = start; base < end; base += 64) {
        int ecnt = min(64, end - base);
        int s_l = 0; float ex_l = 0.0f;
        if (lane < ecnt) {
            s_l = ssrc[base + lane];
            ex_l = __expf(lrelu(a_src2[s_l] + adst));
        }
        lsumA += ex_l;
        int j = 0;
        for (; j + 8 <= ecnt; j += 8) {
            int s0 = __shfl(s_l, j),     s1 = __shfl(s_l, j + 1), s2 = __shfl(s_l, j + 2), s3 = __shfl(s_l, j + 3);
            int s4 = __shfl(s_l, j + 4), s5 = __shfl(s_l, j + 5), s6 = __shfl(s_l, j + 6), s7 = __shfl(s_l, j + 7);
            float f0 = __shfl(ex_l, j),     f1 = __shfl(ex_l, j + 1), f2 = __shfl(ex_l, j + 2), f3 = __shfl(ex_l, j + 3);
            float f4 = __shfl(ex_l, j + 4), f5 = __shfl(ex_l, j + 5), f6 = __shfl(ex_l, j + 6), f7 = __shfl(ex_l, j + 7);
            float g0 = act ? bf2f(h2b[(size_t)s0 * 40 + lane]) : 0.0f;
            float g1 = act ? bf2f(h2b[(size_t)s1 * 40 + lane]) : 0.0f;
            float g2 = act ? bf2f(h2b[(size_t)s2 * 40 + lane]) : 0.0f;
            float g3 = act ? bf2f(h2b[(size_t)s3 * 40 + lane]) : 0.0f;
            float g4 = act ? bf2f(h2b[(size_t)s4 * 40 + lane]) : 0.0f;
            float g5 = act ? bf2f(h2b[(size_t)s5 * 40 + lane]) : 0.0f;
            float g6 = act ? bf2f(h2b[(size_t)s6 * 40 + lane]) : 0.0f;
            float g7 = act ? bf2f(h2b[(size_t)s7 * 40 + lane]) : 0.0f;
            acc0 = fmaf(f0, g0, acc0); acc1 = fmaf(f1, g1, acc1);
            acc0 = fmaf(f2, g2, acc0); acc1 = fmaf(f3, g3, acc1);
            acc0 = fmaf(f4, g4, acc0); acc1 = fmaf(f5, g5, acc1);
            acc0 = fmaf(f6, g6, acc0); acc1 = fmaf(f7, g7, acc1);
        }
        for (; j < ecnt; j++) {
            int sj = __shfl(s_l, j);
            float fj = __shfl(ex_l, j);
            float g = act ? bf2f(h2b[(size_t)sj * 40 + lane]) : 0.0f;
            acc0 = fmaf(fj, g, acc0);
        }
    }
    float t = lsumA;
#pragma unroll
    for (int off = 32; off; off >>= 1) t += __shfl_xor(t, off);
    if (act) out[(size_t)d * 40 + lane] = (acc0 + acc1) / (t + EPS) + bias2[lane];
}

// ---------------- launch ----------------
extern "C" void kernel_launch(void* const* d_in, const int* in_sizes, int n_in,
                              void* d_out, int out_size, void* d_ws, size_t ws_size,
                              hipStream_t stream) {
    const float* x        = (const float*)d_in[0];
    const int*   ei       = (const int*)d_in[1];
    const float* W1       = (const float*)d_in[2];
    const float* att_src1 = (const float*)d_in[3];
    const float* att_dst1 = (const float*)d_in[4];
    const float* bias1    = (const float*)d_in[5];
    const float* W2       = (const float*)d_in[6];
    const float* att_src2 = (const float*)d_in[7];
    const float* att_dst2 = (const float*)d_in[8];
    const float* bias2    = (const float*)d_in[9];
    float* out = (float*)d_out;

    const int N = in_sizes[0] / 128;   // 50000
    const int E = in_sizes[1] / 2;     // 800000
    const int* src = ei;
    const int* dst = ei + E;

    // workspace layout
    float* ws = (float*)d_ws;
    size_t off = 0;
    int*   deg      = (int*)(ws + off); off += (size_t)N;
    int*   rowptr   = (int*)(ws + off); off += (size_t)N + 1;
    int*   cursor   = (int*)(ws + off); off += (size_t)N;
    int*   blocksum = (int*)(ws + off); off += 64;
    int*   ssrc     = (int*)(ws + off); off += (size_t)E;
    unsigned short* h1b = (unsigned short*)(ws + off); off += (size_t)N * 32;  // bf16 N*64
    float* a_src1   = ws + off; off += (size_t)N * 8;
    float* a_dst1   = ws + off; off += (size_t)N * 8;
    float* xx       = ws + off; off += (size_t)N * 64;
    unsigned short* h2b = (unsigned short*)(ws + off); off += (size_t)N * 20;  // bf16 N*40
    float* a_src2   = ws + off; off += (size_t)N;
    float* a_dst2   = ws + off; off += (size_t)N;

    const int B = 256;
    auto g = [](int n) { return (n + 255) / 256; };
    int nb = (N + 1023) / 1024;           // 49
    int G1 = (N + 63) / 64;               // 782 gemm blocks (x1024 edges covers E)
    int D8 = (E / 8 + 255) / 256;         // scatter blocks (8 edges/thread)

    k_zero<<<g(N), B, 0, stream>>>(deg, N);
    k_gemm1_deg<<<G1, B, 0, stream>>>(x, W1, att_src1, att_dst1, h1b, a_src1, a_dst1,
                                      N, dst, deg, E);
    k_scan_local<<<nb, 1024, 0, stream>>>(deg, rowptr, blocksum, N);
    k_scan_add<<<g(N), B, 0, stream>>>(rowptr, blocksum, deg, cursor, N, nb);
    k_scatter<<<D8, B, 0, stream>>>(src, dst, cursor, ssrc, E);

    k_node_agg1<<<(N + 3) / 4, B, 0, stream>>>(rowptr, ssrc, a_src1, a_dst1, h1b, bias1, xx, N);
    k_gemm2<<<G1, B, 0, stream>>>(xx, W2, att_src2, att_dst2, h2b, a_src2, a_dst2, N);
    k_node_agg2<<<(N + 3) / 4, B, 0, stream>>>(rowptr, ssrc, a_src2, a_dst2, h2b, bias2, out, N);
}

// Round 10
// 284.351 us; speedup vs baseline: 1.4917x; 1.4917x over previous
//
#include <hip/hip_runtime.h>
#include <math.h>

#define EPS 1e-16f
__device__ __forceinline__ float lrelu(float v) { return v > 0.0f ? v : 0.2f * v; }

// bf16 pack/unpack (RNE; inputs finite)
__device__ __forceinline__ unsigned short f2bf(float f) {
    unsigned u = __float_as_uint(f);
    u += 0x7FFF + ((u >> 16) & 1);
    return (unsigned short)(u >> 16);
}
__device__ __forceinline__ float bf2f(unsigned short s) {
    return __uint_as_float(((unsigned)s) << 16);
}

// ---------------- CSR build ----------------
__global__ void k_zero(int* __restrict__ deg, int N) {
    int i = blockIdx.x * 256 + threadIdx.x;
    if (i < N) deg[i] = 0;
}

// multi-block scan: per-block local inclusive scan + block sums
__global__ __launch_bounds__(1024) void k_scan_local(const int* __restrict__ deg,
                                                     int* __restrict__ rowptr,
                                                     int* __restrict__ blocksum, int N) {
    __shared__ int sdata[1024];
    int i = blockIdx.x * 1024 + threadIdx.x;
    int v = (i < N) ? deg[i] : 0;
    sdata[threadIdx.x] = v;
    __syncthreads();
    for (int off = 1; off < 1024; off <<= 1) {
        int t = (threadIdx.x >= (unsigned)off) ? sdata[threadIdx.x - off] : 0;
        __syncthreads();
        sdata[threadIdx.x] += t;
        __syncthreads();
    }
    if (i < N) rowptr[i + 1] = sdata[threadIdx.x];
    if (threadIdx.x == 1023) blocksum[blockIdx.x] = sdata[1023];
}

// scan_add with inlined block-sum scan (every block redundantly wave-scans <=64 sums)
__global__ void k_scan_add(int* __restrict__ rowptr, const int* __restrict__ blocksum,
                           const int* __restrict__ deg, int* __restrict__ cursor,
                           int N, int nb) {
    __shared__ int sOff[64];
    int t = threadIdx.x;
    if (t < 64) {
        int v = (t < nb) ? blocksum[t] : 0;
        int incl = v;
#pragma unroll
        for (int off = 1; off < 64; off <<= 1) {
            int u = __shfl_up(incl, off);
            if (t >= off) incl += u;
        }
        sOff[t] = incl - v;
    }
    __syncthreads();
    int i = blockIdx.x * 256 + t;
    if (i >= N) return;
    int val = rowptr[i + 1] + sOff[i >> 10];
    rowptr[i + 1] = val;
    cursor[i] = val - deg[i];
    if (i == 0) rowptr[0] = 0;
}

// 8 edges per thread: 8 independent atomic-return chains in flight
__global__ void k_scatter(const int* __restrict__ src, const int* __restrict__ dst,
                          int* __restrict__ cursor, int* __restrict__ ssrc, int E) {
    int e0 = (blockIdx.x * 256 + threadIdx.x) * 8;
    if (e0 >= E) return;
    int4 sa = *((const int4*)(src + e0)),     sb = *((const int4*)(src + e0 + 4));
    int4 da = *((const int4*)(dst + e0)),     db = *((const int4*)(dst + e0 + 4));
    int p0 = atomicAdd(&cursor[da.x], 1);
    int p1 = atomicAdd(&cursor[da.y], 1);
    int p2 = atomicAdd(&cursor[da.z], 1);
    int p3 = atomicAdd(&cursor[da.w], 1);
    int p4 = atomicAdd(&cursor[db.x], 1);
    int p5 = atomicAdd(&cursor[db.y], 1);
    int p6 = atomicAdd(&cursor[db.z], 1);
    int p7 = atomicAdd(&cursor[db.w], 1);
    ssrc[p0] = sa.x; ssrc[p1] = sa.y; ssrc[p2] = sa.z; ssrc[p3] = sa.w;
    ssrc[p4] = sb.x; ssrc[p5] = sb.y; ssrc[p6] = sb.z; ssrc[p7] = sb.w;
}

// ---------------- layer-1 GEMM (+deg tail): x[N,128] @ W1[128,64] -> h1 (bf16) ----------
// R7/R8-proven inner loop: scalar LDS reads, pitches 129/65 (==1 mod 32), whole K=128,
// launch_bounds(256,2) -> VGPR ~88, NO SPILL (R9's float4-read variant spilled 1.7KB/thread
// of scratch -> 354MB of HBM writes; do not re-vectorize this loop).
// deg histogram is a per-block tail: no separate LDS-hostage blocks (R8's occupancy bug).
#define LDK1 129
#define LDN1 65
__global__ __launch_bounds__(256, 2) void k_gemm1_deg(
    const float* __restrict__ x, const float* __restrict__ W1,
    const float* __restrict__ att_src1, const float* __restrict__ att_dst1,
    unsigned short* __restrict__ h1b, float* __restrict__ a_src1, float* __restrict__ a_dst1,
    int N, const int* __restrict__ dst, int* __restrict__ deg, int E) {
    __shared__ float sX[64 * LDK1];    // [m][k]
    __shared__ float sW[128 * LDN1];   // [k][n]
    int t = threadIdx.x;
    int r0 = blockIdx.x * 64;
    // stage W1 (128x64)
    for (int i = t; i < 2048; i += 256) {        // i = k*16 + n4
        int k = i >> 4, n4 = i & 15;
        float4 v = ((const float4*)W1)[i];
        float* p = sW + k * LDN1 + 4 * n4;
        p[0] = v.x; p[1] = v.y; p[2] = v.z; p[3] = v.w;
    }
    // stage x rows r0..r0+63 (zero-pad tail)
    for (int i = t; i < 2048; i += 256) {        // i = m*32 + k4
        int m = i >> 5, k4 = i & 31;
        int r = r0 + m;
        float4 v = make_float4(0.f, 0.f, 0.f, 0.f);
        if (r < N) v = ((const float4*)(x + (size_t)r * 128))[k4];
        float* p = sX + m * LDK1 + 4 * k4;
        p[0] = v.x; p[1] = v.y; p[2] = v.z; p[3] = v.w;
    }
    __syncthreads();
    int tx = t & 15, ty = t >> 4;                // rows 4*tx.., cols 4*ty..
    const float* pA = sX + 4 * tx * LDK1;
    const float* pB = sW + 4 * ty;
    float c[4][4] = {{0.f}};
#pragma unroll 8
    for (int k = 0; k < 128; k++) {
        float a0 = pA[k], a1 = pA[LDK1 + k], a2 = pA[2 * LDK1 + k], a3 = pA[3 * LDK1 + k];
        const float* pb = pB + k * LDN1;
        float b0 = pb[0], b1 = pb[1], b2 = pb[2], b3 = pb[3];
        c[0][0] = fmaf(a0, b0, c[0][0]); c[0][1] = fmaf(a0, b1, c[0][1]);
        c[0][2] = fmaf(a0, b2, c[0][2]); c[0][3] = fmaf(a0, b3, c[0][3]);
        c[1][0] = fmaf(a1, b0, c[1][0]); c[1][1] = fmaf(a1, b1, c[1][1]);
        c[1][2] = fmaf(a1, b2, c[1][2]); c[1][3] = fmaf(a1, b3, c[1][3]);
        c[2][0] = fmaf(a2, b0, c[2][0]); c[2][1] = fmaf(a2, b1, c[2][1]);
        c[2][2] = fmaf(a2, b2, c[2][2]); c[2][3] = fmaf(a2, b3, c[2][3]);
        c[3][0] = fmaf(a3, b0, c[3][0]); c[3][1] = fmaf(a3, b1, c[3][1]);
        c[3][2] = fmaf(a3, b2, c[3][2]); c[3][3] = fmaf(a3, b3, c[3][3]);
    }
    // epilogue: h1 as bf16 + fused per-head attention dots (fp32 accumulators)
    float as0 = att_src1[4 * ty + 0], as1 = att_src1[4 * ty + 1],
          as2 = att_src1[4 * ty + 2], as3 = att_src1[4 * ty + 3];
    float ad0 = att_dst1[4 * ty + 0], ad1 = att_dst1[4 * ty + 1],
          ad2 = att_dst1[4 * ty + 2], ad3 = att_dst1[4 * ty + 3];
    __syncthreads();                              // done reading sX/sW; reuse sX as partials
    float* sPs = sX;                              // [row][17]
    float* sPd = sX + 64 * 17;
#pragma unroll
    for (int i = 0; i < 4; i++) {
        int row = 4 * tx + i;
        int r = r0 + row;
        if (r < N) {
            ushort4 hv;
            hv.x = f2bf(c[i][0]); hv.y = f2bf(c[i][1]);
            hv.z = f2bf(c[i][2]); hv.w = f2bf(c[i][3]);
            *((ushort4*)(h1b + (size_t)r * 64 + 4 * ty)) = hv;
        }
        sPs[row * 17 + ty] = fmaf(c[i][0], as0, fmaf(c[i][1], as1, fmaf(c[i][2], as2, c[i][3] * as3)));
        sPd[row * 17 + ty] = fmaf(c[i][0], ad0, fmaf(c[i][1], ad1, fmaf(c[i][2], ad2, c[i][3] * ad3)));
    }
    __syncthreads();
    for (int i = t; i < 512; i += 256) {          // i = row*8 + h
        int row = i >> 3, h = i & 7;
        int r = r0 + row;
        if (r < N) {
            a_src1[r * 8 + h] = sPs[row * 17 + 2 * h] + sPs[row * 17 + 2 * h + 1];
            a_dst1[r * 8 + h] = sPd[row * 17 + 2 * h] + sPd[row * 17 + 2 * h + 1];
        }
    }
    // deg tail: this block's 1024-edge slice, 4 atomics in flight per thread.
    // Overlaps with compute of co-resident blocks; deg pre-zeroed by k_zero (prior launch).
    int e0 = blockIdx.x * 1024 + t * 4;
    if (e0 < E) {
        int4 d4 = *((const int4*)(dst + e0));
        atomicAdd(&deg[d4.x], 1);
        atomicAdd(&deg[d4.y], 1);
        atomicAdd(&deg[d4.z], 1);
        atomicAdd(&deg[d4.w], 1);
    }
}

// ---------------- layer 1: per-dst-node softmax + aggregate (one wave per node) ----------------
// no max subtraction (softmax shift-invariant; logits are O(1)); h1 gathered as bf16
__global__ __launch_bounds__(256) void k_node_agg1(
    const int* __restrict__ rowptr, const int* __restrict__ ssrc,
    const float* __restrict__ a_src1, const float* __restrict__ a_dst1,
    const unsigned short* __restrict__ h1b, const float* __restrict__ bias1,
    float* __restrict__ xx, int N) {
    int d = (blockIdx.x * 256 + threadIdx.x) >> 6;
    int lane = threadIdx.x & 63;
    if (d >= N) return;
    int start = rowptr[d], end = rowptr[d + 1];
    int hcol = lane >> 3;   // head owning this output col
    int h8 = lane & 7;      // head this lane covers in edge-parallel phase
    int eoff = lane >> 3;   // edge-in-chunk this lane covers in edge-parallel phase
    float adst8 = a_dst1[d * 8 + h8];
    float acc0 = 0.0f, acc1 = 0.0f, lsumA = 0.0f;
    int base = start;
    for (; base + 8 <= end; base += 8) {
        int s_l = ssrc[base + eoff];
        float ex_l = __expf(lrelu(a_src1[(size_t)s_l * 8 + h8] + adst8));
        lsumA += ex_l;
        int s0 = __shfl(s_l, 0),  s1 = __shfl(s_l, 8),  s2 = __shfl(s_l, 16), s3 = __shfl(s_l, 24);
        int s4 = __shfl(s_l, 32), s5 = __shfl(s_l, 40), s6 = __shfl(s_l, 48), s7 = __shfl(s_l, 56);
        float f0 = __shfl(ex_l, hcol),      f1 = __shfl(ex_l, 8 + hcol);
        float f2 = __shfl(ex_l, 16 + hcol), f3 = __shfl(ex_l, 24 + hcol);
        float f4 = __shfl(ex_l, 32 + hcol), f5 = __shfl(ex_l, 40 + hcol);
        float f6 = __shfl(ex_l, 48 + hcol), f7 = __shfl(ex_l, 56 + hcol);
        float g0 = bf2f(h1b[(size_t)s0 * 64 + lane]), g1 = bf2f(h1b[(size_t)s1 * 64 + lane]);
        float g2 = bf2f(h1b[(size_t)s2 * 64 + lane]), g3 = bf2f(h1b[(size_t)s3 * 64 + lane]);
        float g4 = bf2f(h1b[(size_t)s4 * 64 + lane]), g5 = bf2f(h1b[(size_t)s5 * 64 + lane]);
        float g6 = bf2f(h1b[(size_t)s6 * 64 + lane]), g7 = bf2f(h1b[(size_t)s7 * 64 + lane]);
        acc0 = fmaf(f0, g0, acc0); acc1 = fmaf(f1, g1, acc1);
        acc0 = fmaf(f2, g2, acc0); acc1 = fmaf(f3, g3, acc1);
        acc0 = fmaf(f4, g4, acc0); acc1 = fmaf(f5, g5, acc1);
        acc0 = fmaf(f6, g6, acc0); acc1 = fmaf(f7, g7, acc1);
    }
    int ecnt = end - base;
    if (ecnt > 0) {
        int s_l = 0; float ex_l = 0.0f;
        if (eoff < ecnt) {
            s_l = ssrc[base + eoff];
            ex_l = __expf(lrelu(a_src1[(size_t)s_l * 8 + h8] + adst8));
        }
        lsumA += ex_l;
        for (int j = 0; j < ecnt; j++) {
            int sj = __shfl(s_l, j * 8);
            float fj = __shfl(ex_l, j * 8 + hcol);
            acc0 = fmaf(fj, bf2f(h1b[(size_t)sj * 64 + lane]), acc0);
        }
    }
    float t = lsumA;
    t += __shfl_xor(t, 8); t += __shfl_xor(t, 16); t += __shfl_xor(t, 32);
    float lsum = __shfl(t, hcol);
    float o = (acc0 + acc1) / (lsum + EPS) + bias1[lane];
    xx[(size_t)d * 64 + lane] = o > 0.0f ? o : expm1f(o);   // ELU
}

// ---------------- layer 2 GEMM: xx[N,64] @ W2[64,40] -> h2 (bf16), + fused attention dots ----
#define LDK2 65
#define LDN2 41
__global__ __launch_bounds__(256, 2) void k_gemm2(
    const float* __restrict__ xx, const float* __restrict__ W2,
    const float* __restrict__ att_src2, const float* __restrict__ att_dst2,
    unsigned short* __restrict__ h2b, float* __restrict__ a_src2, float* __restrict__ a_dst2, int N) {
    __shared__ float sX[64 * LDK2];    // [m][k]
    __shared__ float sW[64 * LDN2];    // [k][n]
    int t = threadIdx.x;
    int r0 = blockIdx.x * 64;
    for (int i = t; i < 640; i += 256) {          // i = k*10 + n4
        int k = i / 10, n4 = i - k * 10;
        float4 v = ((const float4*)W2)[i];
        float* p = sW + k * LDN2 + 4 * n4;
        p[0] = v.x; p[1] = v.y; p[2] = v.z; p[3] = v.w;
    }
    for (int i = t; i < 1024; i += 256) {         // i = m*16 + k4
        int m = i >> 4, k4 = i & 15;
        int r = r0 + m;
        float4 v = make_float4(0.f, 0.f, 0.f, 0.f);
        if (r < N) v = ((const float4*)(xx + (size_t)r * 64))[k4];
        float* p = sX + m * LDK2 + 4 * k4;
        p[0] = v.x; p[1] = v.y; p[2] = v.z; p[3] = v.w;
    }
    __syncthreads();
    int tx = t & 15, ty = t >> 4;
    bool act = ty < 10;
    float c[4][4] = {{0.f}};
    if (act) {
        const float* pA = sX + 4 * tx * LDK2;
        const float* pB = sW + 4 * ty;
#pragma unroll 8
        for (int k = 0; k < 64; k++) {
            float a0 = pA[k], a1 = pA[LDK2 + k], a2 = pA[2 * LDK2 + k], a3 = pA[3 * LDK2 + k];
            const float* pb = pB + k * LDN2;
            float b0 = pb[0], b1 = pb[1], b2 = pb[2], b3 = pb[3];
            c[0][0] = fmaf(a0, b0, c[0][0]); c[0][1] = fmaf(a0, b1, c[0][1]);
            c[0][2] = fmaf(a0, b2, c[0][2]); c[0][3] = fmaf(a0, b3, c[0][3]);
            c[1][0] = fmaf(a1, b0, c[1][0]); c[1][1] = fmaf(a1, b1, c[1][1]);
            c[1][2] = fmaf(a1, b2, c[1][2]); c[1][3] = fmaf(a1, b3, c[1][3]);
            c[2][0] = fmaf(a2, b0, c[2][0]); c[2][1] = fmaf(a2, b1, c[2][1]);
            c[2][2] = fmaf(a2, b2, c[2][2]); c[2][3] = fmaf(a2, b3, c[2][3]);
            c[3][0] = fmaf(a3, b0, c[3][0]); c[3][1] = fmaf(a3, b1, c[3][1]);
            c[3][2] = fmaf(a3, b2, c[3][2]); c[3][3] = fmaf(a3, b3, c[3][3]);
        }
    }
    float as0 = 0.f, as1 = 0.f, as2 = 0.f, as3 = 0.f;
    float ad0 = 0.f, ad1 = 0.f, ad2 = 0.f, ad3 = 0.f;
    if (act) {
        as0 = att_src2[4 * ty + 0]; as1 = att_src2[4 * ty + 1];
        as2 = att_src2[4 * ty + 2]; as3 = att_src2[4 * ty + 3];
        ad0 = att_dst2[4 * ty + 0]; ad1 = att_dst2[4 * ty + 1];
        ad2 = att_dst2[4 * ty + 2]; ad3 = att_dst2[4 * ty + 3];
    }
    __syncthreads();                              // reuse sX as partials [row][11]
    float* sPs = sX;
    float* sPd = sX + 64 * 11;
#pragma unroll
    for (int i = 0; i < 4; i++) {
        int row = 4 * tx + i;
        int r = r0 + row;
        if (act) {
            if (r < N) {
                ushort4 hv;
                hv.x = f2bf(c[i][0]); hv.y = f2bf(c[i][1]);
                hv.z = f2bf(c[i][2]); hv.w = f2bf(c[i][3]);
                *((ushort4*)(h2b + (size_t)r * 40 + 4 * ty)) = hv;
            }
            sPs[row * 11 + ty] = fmaf(c[i][0], as0, fmaf(c[i][1], as1, fmaf(c[i][2], as2, c[i][3] * as3)));
            sPd[row * 11 + ty] = fmaf(c[i][0], ad0, fmaf(c[i][1], ad1, fmaf(c[i][2], ad2, c[i][3] * ad3)));
        }
    }
    __syncthreads();
    if (t < 64) {
        int r = r0 + t;
        if (r < N) {
            float ps = 0.f, pd = 0.f;
#pragma unroll
            for (int j = 0; j < 10; j++) {
                ps += sPs[t * 11 + j];
                pd += sPd[t * 11 + j];
            }
            a_src2[r] = ps;
            a_dst2[r] = pd;
        }
    }
}

// ---------------- layer 2: per-dst-node softmax + aggregate (h2 gathered as bf16) --------
__global__ __launch_bounds__(256) void k_node_agg2(
    const int* __restrict__ rowptr, const int* __restrict__ ssrc,
    const float* __restrict__ a_src2, const float* __restrict__ a_dst2,
    const unsigned short* __restrict__ h2b, const float* __restrict__ bias2,
    float* __restrict__ out, int N) {
    int d = (blockIdx.x * 256 + threadIdx.x) >> 6;
    int lane = threadIdx.x & 63;
    if (d >= N) return;
    int start = rowptr[d], end = rowptr[d + 1];
    float adst = a_dst2[d];
    bool act = lane < 40;
    float acc0 = 0.0f, acc1 = 0.0f, lsumA = 0.0f;
    for (int base = start; base < end; base += 64) {
        int ecnt = min(64, end - base);
        int s_l = 0; float ex_l = 0.0f;
        if (lane < ecnt) {
            s_l = ssrc[base + lane];
            ex_l = __expf(lrelu(a_src2[s_l] + adst));
        }
        lsumA += ex_l;
        int j = 0;
        for (; j + 8 <= ecnt; j += 8) {
            int s0 = __shfl(s_l, j),     s1 = __shfl(s_l, j + 1), s2 = __shfl(s_l, j + 2), s3 = __shfl(s_l, j + 3);
            int s4 = __shfl(s_l, j + 4), s5 = __shfl(s_l, j + 5), s6 = __shfl(s_l, j + 6), s7 = __shfl(s_l, j + 7);
            float f0 = __shfl(ex_l, j),     f1 = __shfl(ex_l, j + 1), f2 = __shfl(ex_l, j + 2), f3 = __shfl(ex_l, j + 3);
            float f4 = __shfl(ex_l, j + 4), f5 = __shfl(ex_l, j + 5), f6 = __shfl(ex_l, j + 6), f7 = __shfl(ex_l, j + 7);
            float g0 = act ? bf2f(h2b[(size_t)s0 * 40 + lane]) : 0.0f;
            float g1 = act ? bf2f(h2b[(size_t)s1 * 40 + lane]) : 0.0f;
            float g2 = act ? bf2f(h2b[(size_t)s2 * 40 + lane]) : 0.0f;
            float g3 = act ? bf2f(h2b[(size_t)s3 * 40 + lane]) : 0.0f;
            float g4 = act ? bf2f(h2b[(size_t)s4 * 40 + lane]) : 0.0f;
            float g5 = act ? bf2f(h2b[(size_t)s5 * 40 + lane]) : 0.0f;
            float g6 = act ? bf2f(h2b[(size_t)s6 * 40 + lane]) : 0.0f;
            float g7 = act ? bf2f(h2b[(size_t)s7 * 40 + lane]) : 0.0f;
            acc0 = fmaf(f0, g0, acc0); acc1 = fmaf(f1, g1, acc1);
            acc0 = fmaf(f2, g2, acc0); acc1 = fmaf(f3, g3, acc1);
            acc0 = fmaf(f4, g4, acc0); acc1 = fmaf(f5, g5, acc1);
            acc0 = fmaf(f6, g6, acc0); acc1 = fmaf(f7, g7, acc1);
        }
        for (; j < ecnt; j++) {
            int sj = __shfl(s_l, j);
            float fj = __shfl(ex_l, j);
            float g = act ? bf2f(h2b[(size_t)sj * 40 + lane]) : 0.0f;
            acc0 = fmaf(fj, g, acc0);
        }
    }
    float t = lsumA;
#pragma unroll
    for (int off = 32; off; off >>= 1) t += __shfl_xor(t, off);
    if (act) out[(size_t)d * 40 + lane] = (acc0 + acc1) / (t + EPS) + bias2[lane];
}

// ---------------- launch ----------------
extern "C" void kernel_launch(void* const* d_in, const int* in_sizes, int n_in,
                              void* d_out, int out_size, void* d_ws, size_t ws_size,
                              hipStream_t stream) {
    const float* x        = (const float*)d_in[0];
    const int*   ei       = (const int*)d_in[1];
    const float* W1       = (const float*)d_in[2];
    const float* att_src1 = (const float*)d_in[3];
    const float* att_dst1 = (const float*)d_in[4];
    const float* bias1    = (const float*)d_in[5];
    const float* W2       = (const float*)d_in[6];
    const float* att_src2 = (const float*)d_in[7];
    const float* att_dst2 = (const float*)d_in[8];
    const float* bias2    = (const float*)d_in[9];
    float* out = (float*)d_out;

    const int N = in_sizes[0] / 128;   // 50000
    const int E = in_sizes[1] / 2;     // 800000
    const int* src = ei;
    const int* dst = ei + E;

    // workspace layout
    float* ws = (float*)d_ws;
    size_t off = 0;
    int*   deg      = (int*)(ws + off); off += (size_t)N;
    int*   rowptr   = (int*)(ws + off); off += (size_t)N + 1;
    int*   cursor   = (int*)(ws + off); off += (size_t)N;
    int*   blocksum = (int*)(ws + off); off += 64;
    int*   ssrc     = (int*)(ws + off); off += (size_t)E;
    unsigned short* h1b = (unsigned short*)(ws + off); off += (size_t)N * 32;  // bf16 N*64
    float* a_src1   = ws + off; off += (size_t)N * 8;
    float* a_dst1   = ws + off; off += (size_t)N * 8;
    float* xx       = ws + off; off += (size_t)N * 64;
    unsigned short* h2b = (unsigned short*)(ws + off); off += (size_t)N * 20;  // bf16 N*40
    float* a_src2   = ws + off; off += (size_t)N;
    float* a_dst2   = ws + off; off += (size_t)N;

    const int B = 256;
    auto g = [](int n) { return (n + 255) / 256; };
    int nb = (N + 1023) / 1024;           // 49
    int G1 = (N + 63) / 64;               // 782 gemm blocks (x1024 edges covers E)
    int D8 = (E / 8 + 255) / 256;         // scatter blocks (8 edges/thread)

    k_zero<<<g(N), B, 0, stream>>>(deg, N);
    k_gemm1_deg<<<G1, B, 0, stream>>>(x, W1, att_src1, att_dst1, h1b, a_src1, a_dst1,
                                      N, dst, deg, E);
    k_scan_local<<<nb, 1024, 0, stream>>>(deg, rowptr, blocksum, N);
    k_scan_add<<<g(N), B, 0, stream>>>(rowptr, blocksum, deg, cursor, N, nb);
    k_scatter<<<D8, B, 0, stream>>>(src, dst, cursor, ssrc, E);

    k_node_agg1<<<(N + 3) / 4, B, 0, stream>>>(rowptr, ssrc, a_src1, a_dst1, h1b, bias1, xx, N);
    k_gemm2<<<G1, B, 0, stream>>>(xx, W2, att_src2, att_dst2, h2b, a_src2, a_dst2, N);
    k_node_agg2<<<(N + 3) / 4, B, 0, stream>>>(rowptr, ssrc, a_src2, a_dst2, h2b, bias2, out, N);
}